// Round 7
// baseline (307.931 us; speedup 1.0000x reference)
//
#include <hip/hip_runtime.h>

// SepConv: out[b,c,i,j] = sum_{u,v} img[b,c,i+u,j+v] * vert[b,u,i,j] * hori[b,v,i,j]
// B=8, C=3, W=H=512, K=13, Wo=Ho=500.
//
// R7: continuous-HBM-demand pipeline. R6 (single-shot stage->barrier->compute
// per block) phase-locked all blocks: HBM oscillated between 40MB burst
// queues and idle compute phases -> 2.07 TB/s. Here each block owns a stream
// of half-row tasks (grid=768 = 3 blocks/CU at 53KB LDS) with DOUBLE-BUFFERED
// weight staging: fire next task's 26KB of global_load_lds DMA right after
// the barrier, then compute the current task from the other buffer. Every
// block keeps ~26KB outstanding at all times -> ~78KB/CU in flight (Little's
// law needs ~9KB for 6.3 TB/s). The barrier's vmcnt(0) only drains the
// remainder of a transfer that flew during compute.

#define KK 13
#define NB 8
#define NC 3
#define IW 512
#define IH 512
#define WO 500
#define HO 500
#define KHW 250000        // WO*HO
#define RS4 62500         // KHW/4: float4 stride between u-slices
#define QROW 125          // float4 quads per full 500-col row
#define NTX 64
#define NTY 3
#define NT 192            // 64 j-lanes x 3 channels
#define SLOT (KK * 64)    // 832 float4 per array per half-row task
#define NTASK (NB * 2 * WO)  // 8000 half-row tasks
#define NBLK 768          // exactly 3 blocks/CU on 256 CUs

typedef __attribute__((address_space(1))) const void g_void;
typedef __attribute__((address_space(3))) void l_void;

__global__ __launch_bounds__(NT) void sepconv_kernel(
    const float* __restrict__ img,
    const float* __restrict__ hori,
    const float* __restrict__ vert,
    float* __restrict__ out)
{
    __shared__ float4 smem[2][2][SLOT];   // [buf][vert=0/hori=1][u*64+q], 53248 B

    const int tx = threadIdx.x;           // 0..63 = lane = j-quad within half
    const int ty = threadIdx.y;           // channel
    const int tid = ty * NTX + tx;

    // task t -> (b = t/1000, half = (t%1000)/500, i = t%500)
    auto stage = [&](int t, int sb) {
        const unsigned bb   = (unsigned)t / 1000u;
        const unsigned rem  = (unsigned)t - bb * 1000u;
        const unsigned half = rem / 500u;
        const unsigned ii   = rem - half * 500u;
        const size_t base = (size_t)bb * KK * KHW + (size_t)ii * HO + half * 256;
        const float4* v4 = (const float4*)(vert + base);
        const float4* h4 = (const float4*)(hori + base);
        const int qlim = half ? 61 : 64;  // half 1 holds quads 64..124
        #pragma unroll
        for (int f0 = 0; f0 < SLOT; f0 += NT) {
            const int f = f0 + tid;
            if (f < SLOT) {               // last round: wave ty=0 only (uniform)
                const int u = f >> 6;
                const int q = f & 63;
                if (q < qlim) {
                    __builtin_amdgcn_global_load_lds(
                        (g_void*)(v4 + (size_t)u * RS4 + q),
                        (l_void*)&smem[sb][0][f], 16, 0, 0);
                    __builtin_amdgcn_global_load_lds(
                        (g_void*)(h4 + (size_t)u * RS4 + q),
                        (l_void*)&smem[sb][1][f], 16, 0, 0);
                }
            }
        }
    };

    int t = blockIdx.x;
    int s = 0;
    stage(t, 0);

    while (t < NTASK) {
        const int nt = t + NBLK;
        __syncthreads();                  // buf s ready (its DMAs flew during prior compute)
        if (nt < NTASK) stage(nt, s ^ 1); // fire next task's DMA before computing

        // ---- compute task t from buffer s ----
        const unsigned bb   = (unsigned)t / 1000u;
        const unsigned rem  = (unsigned)t - bb * 1000u;
        const unsigned half = rem / 500u;
        const unsigned ii   = rem - half * 500u;
        const int tj = (int)half * 64 + tx;
        if (tj < QROW) {
            const int j0 = tj * 4;
            const float* ibase = img + (((size_t)(bb * NC + ty) * IW) + ii) * IH + j0;

            float tmp[4][KK];
            #pragma unroll
            for (int jq = 0; jq < 4; ++jq)
                #pragma unroll
                for (int v = 0; v < KK; ++v)
                    tmp[jq][v] = 0.0f;

            float4 c0 = *(const float4*)(ibase + 0);
            float4 c1 = *(const float4*)(ibase + 4);
            float4 c2 = *(const float4*)(ibase + 8);
            float4 c3 = *(const float4*)(ibase + 12);

            #pragma unroll
            for (int u = 0; u < KK; ++u) {
                float4 n0, n1, n2, n3;
                if (u < KK - 1) {
                    const float* rp = ibase + (size_t)(u + 1) * IH;
                    n0 = *(const float4*)(rp + 0);
                    n1 = *(const float4*)(rp + 4);
                    n2 = *(const float4*)(rp + 8);
                    n3 = *(const float4*)(rp + 12);
                }

                const float4 vt = smem[s][0][u * 64 + tx];   // ds_read_b128

                float row[16];
                row[0]  = c0.x; row[1]  = c0.y; row[2]  = c0.z; row[3]  = c0.w;
                row[4]  = c1.x; row[5]  = c1.y; row[6]  = c1.z; row[7]  = c1.w;
                row[8]  = c2.x; row[9]  = c2.y; row[10] = c2.z; row[11] = c2.w;
                row[12] = c3.x; row[13] = c3.y; row[14] = c3.z; row[15] = c3.w;

                #pragma unroll
                for (int v = 0; v < KK; ++v) {
                    tmp[0][v] += row[0 + v] * vt.x;
                    tmp[1][v] += row[1 + v] * vt.y;
                    tmp[2][v] += row[2 + v] * vt.z;
                    tmp[3][v] += row[3 + v] * vt.w;
                }

                if (u < KK - 1) {
                    c0 = n0; c1 = n1; c2 = n2; c3 = n3;
                }
            }

            float4 o = make_float4(0.f, 0.f, 0.f, 0.f);
            #pragma unroll
            for (int v = 0; v < KK; ++v) {
                const float4 hv = smem[s][1][v * 64 + tx];
                o.x += tmp[0][v] * hv.x;
                o.y += tmp[1][v] * hv.y;
                o.z += tmp[2][v] * hv.z;
                o.w += tmp[3][v] * hv.w;
            }

            float* op = out + (((size_t)(bb * NC + ty) * WO) + ii) * HO + j0;
            *(float4*)op = o;
        }

        t = nt;
        s ^= 1;
    }
}

extern "C" void kernel_launch(void* const* d_in, const int* in_sizes, int n_in,
                              void* d_out, int out_size, void* d_ws, size_t ws_size,
                              hipStream_t stream) {
    const float* img  = (const float*)d_in[0];
    const float* hori = (const float*)d_in[1];
    const float* vert = (const float*)d_in[2];
    float* out = (float*)d_out;

    dim3 block(NTX, NTY, 1);      // 64 j-quads x 3 channels
    dim3 grid(NBLK, 1, 1);        // persistent-ish: 3 blocks/CU, task-strided
    hipLaunchKernelGGL(sepconv_kernel, grid, block, 0, stream, img, hori, vert, out);
}